// Round 2
// baseline (541.524 us; speedup 1.0000x reference)
//
#include <hip/hip_runtime.h>
#include <hip/hip_bf16.h>
#include <cstdint>
#include <cstddef>

#define S_LEN 512
#define BATCH 32
#define EDIM  300
#define KPAD  320
#define K3    960   // [Xh|Xh|Xl] / [Wh|Wl|Wh]
#define HDIM  128
#define NGATE 512   // 4*H
#define NCOLS 1024  // fwd 512 + bwd 512

typedef float    f2  __attribute__((ext_vector_type(2)));
typedef float    f4v __attribute__((ext_vector_type(4)));
typedef short    short8 __attribute__((ext_vector_type(8)));
typedef _Float16 h2  __attribute__((ext_vector_type(2)));

__device__ __forceinline__ float sigm_fast(float x) {
    return __builtin_amdgcn_rcpf(1.f + __expf(-x));
}
__device__ __forceinline__ float tanh_fast(float x) {
    return 2.f * sigm_fast(2.f * x) - 1.f;
}

// DPP cross-lane move (VALU pipe).
// quad_perm bcasts: 0x00/0x55/0xAA/0xFF = lane 0/1/2/3 of quad to all.
// row rotates: 0x124 = row_ror:4, 0x128 = row_ror:8 (verified R1-R7).
template <int CTRL>
__device__ __forceinline__ float dpp_mov(float x) {
    int r = __builtin_amdgcn_update_dpp(0, __float_as_int(x), CTRL, 0xF, 0xF, true);
    return __int_as_float(r);
}

// pack two f32 -> f16x2 (v_cvt_pkrtz_f16_f32)
__device__ __forceinline__ h2 pk_f16(float a, float b) {
    auto r = __builtin_amdgcn_cvt_pkrtz(a, b);
    return __builtin_bit_cast(h2, r);
}

__device__ __forceinline__ void bf16_split(float v, ushort& hi, ushort& lo) {
    __hip_bfloat16 hb = __float2bfloat16(v);
    float hf = __bfloat162float(hb);
    __hip_bfloat16 lb = __float2bfloat16(v - hf);
    hi = *reinterpret_cast<ushort*>(&hb);
    lo = *reinterpret_cast<ushort*>(&lb);
}

// ---------------------------------------------------------------------------
// Kernel 1: embeddings -> Xcat (bf16 hi/lo split), row = [Xh | Xh | Xl]
// ---------------------------------------------------------------------------
__global__ void embed_xcat(const int* __restrict__ word_ids,
                           const int* __restrict__ deps_ids,
                           const float* __restrict__ word_table,
                           const float* __restrict__ dep_table,
                           ushort* __restrict__ Xcat) {
    int pos = blockIdx.x;
    int b = pos >> 9, s = pos & (S_LEN - 1);
    int wid = word_ids[b * 3 * S_LEN + S_LEN + s];
    const int* dp = deps_ids + (size_t)pos * 8;
    int ids[8];
    int cnt = 0;
#pragma unroll
    for (int d = 0; d < 8; ++d) {
        int id = dp[d];
        ids[d] = id;
        cnt += (id != 0 && id != 1) ? 1 : 0;
    }
    float inv = 0.5f / (float)((cnt > 0) ? cnt : 1);
    const float* wr = word_table + (size_t)wid * EDIM;
    ushort* xr = Xcat + (size_t)pos * K3;
    for (int e = threadIdx.x; e < KPAD; e += 128) {
        float v = 0.f;
        if (e < EDIM) {
            float w = wr[e];
            float dsum = 0.f;
#pragma unroll
            for (int d = 0; d < 8; ++d) {
                if (ids[d] != 0 && ids[d] != 1) dsum += dep_table[ids[d] * EDIM + e];
            }
            v = (cnt > 0) ? (0.5f * w + dsum * inv) : w;
        }
        ushort hu, lu;
        bf16_split(v, hu, lu);
        xr[e] = hu;
        xr[KPAD + e] = hu;
        xr[2 * KPAD + e] = lu;
    }
}

// ---------------------------------------------------------------------------
// Kernel 1b: Wih -> Wcat, row n = [Wh | Wl | Wh]
// ---------------------------------------------------------------------------
__global__ void wcat_kernel(const float* __restrict__ Wih_f,
                            const float* __restrict__ Wih_b,
                            ushort* __restrict__ Wcat) {
    int n = blockIdx.x;
    const float* src = (n < NGATE) ? (Wih_f + (size_t)n * EDIM)
                                   : (Wih_b + (size_t)(n - NGATE) * EDIM);
    ushort* wr = Wcat + (size_t)n * K3;
    for (int e = threadIdx.x; e < KPAD; e += 128) {
        float v = (e < EDIM) ? src[e] : 0.f;
        ushort hu, lu;
        bf16_split(v, hu, lu);
        wr[e] = hu;
        wr[KPAD + e] = lu;
        wr[2 * KPAD + e] = hu;
    }
}

// ---------------------------------------------------------------------------
// Kernel 2: MFMA GEMM (bf16x3), unchanged from R7 (verified).
// ---------------------------------------------------------------------------
#define LSTR 40
__global__ __launch_bounds__(256) void gemm_mfma(
        const ushort* __restrict__ Xcat,
        const ushort* __restrict__ Wcat,
        const float* __restrict__ b_f, const float* __restrict__ b_b,
        float* __restrict__ pre) {
    __shared__ ushort Asub[128 * LSTR];
    __shared__ ushort Bsub[128 * LSTR];
    int tid = threadIdx.x;
    int wave = tid >> 6, lane = tid & 63;
    int lid = lane & 15, quad = lane >> 4;
    int m0 = blockIdx.x * 128, n0 = blockIdx.y * 128;
    int wm = (wave >> 1) * 64, wn = (wave & 1) * 64;

    f4v acc[4][4];
#pragma unroll
    for (int i = 0; i < 4; ++i)
#pragma unroll
        for (int j = 0; j < 4; ++j) acc[i][j] = (f4v)0.f;

    float bias[4];
#pragma unroll
    for (int nt = 0; nt < 4; ++nt) {
        int n = n0 + wn + nt * 16 + lid;
        bias[nt] = (n < NGATE) ? b_f[n] : b_b[n - NGATE];
    }

    int c0 = tid, c1 = tid + 256;
    const ushort* aptr0 = Xcat + (size_t)(m0 + (c0 >> 2)) * K3 + (c0 & 3) * 8;
    const ushort* aptr1 = Xcat + (size_t)(m0 + (c1 >> 2)) * K3 + (c1 & 3) * 8;
    const ushort* bptr0 = Wcat + (size_t)(n0 + (c0 >> 2)) * K3 + (c0 & 3) * 8;
    const ushort* bptr1 = Wcat + (size_t)(n0 + (c1 >> 2)) * K3 + (c1 & 3) * 8;
    int la0 = (c0 >> 2) * LSTR + (c0 & 3) * 8;
    int la1 = (c1 >> 2) * LSTR + (c1 & 3) * 8;

    short8 ra0 = *(const short8*)(aptr0);
    short8 ra1 = *(const short8*)(aptr1);
    short8 rb0 = *(const short8*)(bptr0);
    short8 rb1 = *(const short8*)(bptr1);

    for (int k0 = 0; k0 < K3; k0 += 32) {
        __syncthreads();
        *(short8*)&Asub[la0] = ra0;
        *(short8*)&Asub[la1] = ra1;
        *(short8*)&Bsub[la0] = rb0;
        *(short8*)&Bsub[la1] = rb1;
        __syncthreads();
        if (k0 + 32 < K3) {
            ra0 = *(const short8*)(aptr0 + k0 + 32);
            ra1 = *(const short8*)(aptr1 + k0 + 32);
            rb0 = *(const short8*)(bptr0 + k0 + 32);
            rb1 = *(const short8*)(bptr1 + k0 + 32);
        }
        short8 aF[4], bF[4];
#pragma unroll
        for (int mt = 0; mt < 4; ++mt)
            aF[mt] = *(const short8*)&Asub[(wm + mt * 16 + lid) * LSTR + quad * 8];
#pragma unroll
        for (int nt = 0; nt < 4; ++nt)
            bF[nt] = *(const short8*)&Bsub[(wn + nt * 16 + lid) * LSTR + quad * 8];
#pragma unroll
        for (int mt = 0; mt < 4; ++mt)
#pragma unroll
            for (int nt = 0; nt < 4; ++nt)
                acc[mt][nt] = __builtin_amdgcn_mfma_f32_16x16x32_bf16(
                    aF[mt], bF[nt], acc[mt][nt], 0, 0, 0);
    }

#pragma unroll
    for (int mt = 0; mt < 4; ++mt)
#pragma unroll
        for (int nt = 0; nt < 4; ++nt) {
            int n = n0 + wn + nt * 16 + lid;
#pragma unroll
            for (int r = 0; r < 4; ++r) {
                int m = m0 + wm + mt * 16 + quad * 4 + r;
                pre[(size_t)m * NCOLS + n] = acc[mt][nt][r] + bias[nt];
            }
        }
}

// ---------------------------------------------------------------------------
// Kernel 3: LSTM recurrence v7 — 512 threads (2 waves/SIMD) for latency
// hiding.  64 blocks (b,dir) x 512 threads.  Lane l, wave wv:
//   tau = l&3 (gate type), ks = (l>>2)&3 (k-slice [32ks,32ks+32)),
//   hi2 = l>>4, hbase = 16*wv + 4*hi2.
// Lane computes partials for 4 gate rows j=0..3: row = tau*128 + hbase+j.
// k-combine across the 4 ks copies (lanes 4 apart within the 16-row) via
// the verified ror:4+ror:8 rotate-reduce.  Each lane then owns exactly ONE
// gate: (tau, hbase+ks).  Activation is tau-split: tau 0/1/3 compute
// sigmoid, tau 2 computes tanh (sharing one exp: exp(-2g) = exp(-g)^2);
// the quad_perm broadcasts distribute the ACTIVATED values, so per-lane
// transcendentals drop from ~10 to ~5 and only 4 DPP bcasts are needed.
// One lgkm-only barrier/step; global pre prefetch stays in flight.
// ---------------------------------------------------------------------------
__global__ __launch_bounds__(512, 2) void lstm_rec(
        const float* __restrict__ pre,
        const float* __restrict__ Whh_f, const float* __restrict__ Whh_b,
        float* __restrict__ pooled) {
    __shared__ _Float16 h_s[HDIM];
    int t = threadIdx.x;
    int lane = t & 63;
    int wv = t >> 6;                         // 0..7
    int tau = lane & 3;
    int ks  = (lane >> 2) & 3;
    int hi2 = lane >> 4;                     // 0..3
    int hbase = wv * 16 + hi2 * 4;           // hidx(j) = hbase + j, j=0..3
    int b = blockIdx.x >> 1;
    int dir = blockIdx.x & 1;
    const float* Whh = dir ? Whh_b : Whh_f;

    // f16 weights: w[j][q] = Whh[tau*128 + hbase+j][32ks + 2q, +1]  (64 VGPRs)
    h2 w[4][16];
#pragma unroll
    for (int j = 0; j < 4; ++j) {
        const float* rp = Whh + (size_t)(tau * HDIM + hbase + j) * HDIM + ks * 32;
#pragma unroll
        for (int q = 0; q < 16; ++q) w[j][q] = pk_f16(rp[2 * q], rp[2 * q + 1]);
    }

    float c = 0.f;
    float hmax = -1e30f;
    if (t < 64) ((uint*)h_s)[t] = 0u;       // zero 128 f16

    // owned pre column: gate (tau, hbase+ks)
    const float* pZ = pre + (size_t)b * S_LEN * NCOLS + dir * NGATE
                    + tau * HDIM + hbase + ks;
    int s0 = dir ? (S_LEN - 1) : 0;
    int sd = dir ? -1 : 1;
    long stride = (long)sd * NCOLS;
    const float* pf = pZ + (long)s0 * NCOLS;
    float pn1 = *pf; pf += stride;
    float pn2 = *pf; pf += stride;

    bool is_g = (tau == 2);
    int hZ = hbase + ks;                    // hidx this lane's quad owns
    const h2* hp = (const h2*)h_s + ks * 16;

    asm volatile("s_waitcnt lgkmcnt(0)\n\ts_barrier" ::: "memory");

    for (int step = 0; step < S_LEN; ++step) {
        float cur = pn1;
        pn1 = pn2;
        if (step + 2 < S_LEN) pn2 = *pf;
        pf += stride;

        // h slice for this lane's k-range: 16 h2 = 64 B = 4 x ds_read_b128
        h2 hh[16];
#pragma unroll
        for (int q = 0; q < 16; ++q) hh[q] = hp[q];

        // 4 partial dots over the owned k-slice (4 independent chains)
        float P[4];
#pragma unroll
        for (int j = 0; j < 4; ++j) {
            float acc = 0.f;
#pragma unroll
            for (int q = 0; q < 16; ++q)
                acc = __builtin_amdgcn_fdot2(w[j][q], hh[q], acc, false);
            P[j] = acc;
        }

        // k-combine across the 4 ks lanes (4 apart): verified rotate-reduce
        float R[4];
#pragma unroll
        for (int j = 0; j < 4; ++j) {
            float r = P[j];
            r += dpp_mov<0x124>(r);   // row_ror:4
            r += dpp_mov<0x128>(r);   // row_ror:8
            R[j] = r;                 // full dot for gate (tau, hbase+j)
        }

        // this lane's owned gate: j = ks
        float X01 = (ks & 1) ? R[1] : R[0];
        float X23 = (ks & 1) ? R[3] : R[2];
        float X   = (ks & 2) ? X23 : X01;
        float g   = X + cur;

        // tau-split activation: sigm for i/f/o (tau 0,1,3), tanh for g (tau 2)
        // exp(-2g) = exp(-g)^2 -> one v_exp serves both.
        float e  = __expf(-g);
        float sg = __builtin_amdgcn_rcpf(1.f + e);
        float th = 2.f * __builtin_amdgcn_rcpf(1.f + e * e) - 1.f;
        float act = is_g ? th : sg;

        // quad broadcasts of the ACTIVATED gates for owned hidx
        float ai = dpp_mov<0x00>(act);
        float af = dpp_mov<0x55>(act);
        float ag = dpp_mov<0xAA>(act);
        float ao = dpp_mov<0xFF>(act);

        c = af * c + ai * ag;
        float h = ao * tanh_fast(c);
        hmax = fmaxf(hmax, h);

        if (tau == 0) h_s[hZ] = (_Float16)h;
        asm volatile("s_waitcnt lgkmcnt(0)\n\ts_barrier" ::: "memory");
    }

    if (tau == 0) pooled[b * 256 + dir * HDIM + hZ] = hmax;
}

// ---------------------------------------------------------------------------
// Kernel 4: classifier (unchanged)
// ---------------------------------------------------------------------------
__global__ void cls_kernel(const float* __restrict__ pooled,
                           const float* __restrict__ W_cls,
                           const float* __restrict__ b_cls,
                           float* __restrict__ out) {
    int i = threadIdx.x;
    if (i < BATCH * 5) {
        int b = i / 5, l = i % 5;
        float acc = b_cls[l];
        const float* p = pooled + b * 256;
        const float* w = W_cls + l * 256;
#pragma unroll 8
        for (int j = 0; j < 256; ++j) acc = fmaf(p[j], w[j], acc);
        out[i] = acc;
    }
}

// ---------------------------------------------------------------------------
extern "C" void kernel_launch(void* const* d_in, const int* in_sizes, int n_in,
                              void* d_out, int out_size, void* d_ws, size_t ws_size,
                              hipStream_t stream) {
    const int*   word_ids   = (const int*)d_in[0];
    const int*   deps_ids   = (const int*)d_in[1];
    const float* word_table = (const float*)d_in[2];
    const float* dep_table  = (const float*)d_in[3];
    const float* Wih_f      = (const float*)d_in[4];
    const float* Whh_f      = (const float*)d_in[5];
    const float* b_f        = (const float*)d_in[6];
    const float* Wih_b      = (const float*)d_in[7];
    const float* Whh_b      = (const float*)d_in[8];
    const float* b_b        = (const float*)d_in[9];
    const float* W_cls      = (const float*)d_in[10];
    const float* b_cls      = (const float*)d_in[11];
    float* out = (float*)d_out;

    float*  pre    = (float*)d_ws;
    float*  pooled = pre + (size_t)BATCH * S_LEN * NCOLS;
    ushort* Xcat   = (ushort*)(pooled + BATCH * 256);
    ushort* Wcat   = Xcat + (size_t)BATCH * S_LEN * K3;

    embed_xcat<<<BATCH * S_LEN, 128, 0, stream>>>(word_ids, deps_ids,
                                                  word_table, dep_table, Xcat);
    wcat_kernel<<<NCOLS, 128, 0, stream>>>(Wih_f, Wih_b, Wcat);
    gemm_mfma<<<dim3(128, 8), 256, 0, stream>>>(Xcat, Wcat, b_f, b_b, pre);
    lstm_rec<<<64, 512, 0, stream>>>(pre, Whh_f, Whh_b, pooled);
    cls_kernel<<<1, 192, 0, stream>>>(pooled, W_cls, b_cls, out);
}

// Round 3
// 512.503 us; speedup vs baseline: 1.0566x; 1.0566x over previous
//
#include <hip/hip_runtime.h>
#include <hip/hip_bf16.h>
#include <cstdint>
#include <cstddef>

#define S_LEN 512
#define BATCH 32
#define EDIM  300
#define KPAD  320
#define K3    960   // [Xh|Xh|Xl] / [Wh|Wl|Wh]
#define HDIM  128
#define NGATE 512   // 4*H
#define NCOLS 1024  // fwd 512 + bwd 512

typedef float    f2  __attribute__((ext_vector_type(2)));
typedef float    f4v __attribute__((ext_vector_type(4)));
typedef short    short8 __attribute__((ext_vector_type(8)));
typedef _Float16 h2  __attribute__((ext_vector_type(2)));

// pack two f32 -> f16x2 (v_cvt_pkrtz_f16_f32)
__device__ __forceinline__ h2 pk_f16(float a, float b) {
    auto r = __builtin_amdgcn_cvt_pkrtz(a, b);
    return __builtin_bit_cast(h2, r);
}

__device__ __forceinline__ void bf16_split(float v, ushort& hi, ushort& lo) {
    __hip_bfloat16 hb = __float2bfloat16(v);
    float hf = __bfloat162float(hb);
    __hip_bfloat16 lb = __float2bfloat16(v - hf);
    hi = *reinterpret_cast<ushort*>(&hb);
    lo = *reinterpret_cast<ushort*>(&lb);
}

// ---------------------------------------------------------------------------
// Kernel 1: embeddings -> Xcat (bf16 hi/lo split), row = [Xh | Xh | Xl]
// ---------------------------------------------------------------------------
__global__ void embed_xcat(const int* __restrict__ word_ids,
                           const int* __restrict__ deps_ids,
                           const float* __restrict__ word_table,
                           const float* __restrict__ dep_table,
                           ushort* __restrict__ Xcat) {
    int pos = blockIdx.x;
    int b = pos >> 9, s = pos & (S_LEN - 1);
    int wid = word_ids[b * 3 * S_LEN + S_LEN + s];
    const int* dp = deps_ids + (size_t)pos * 8;
    int ids[8];
    int cnt = 0;
#pragma unroll
    for (int d = 0; d < 8; ++d) {
        int id = dp[d];
        ids[d] = id;
        cnt += (id != 0 && id != 1) ? 1 : 0;
    }
    float inv = 0.5f / (float)((cnt > 0) ? cnt : 1);
    const float* wr = word_table + (size_t)wid * EDIM;
    ushort* xr = Xcat + (size_t)pos * K3;
    for (int e = threadIdx.x; e < KPAD; e += 128) {
        float v = 0.f;
        if (e < EDIM) {
            float w = wr[e];
            float dsum = 0.f;
#pragma unroll
            for (int d = 0; d < 8; ++d) {
                if (ids[d] != 0 && ids[d] != 1) dsum += dep_table[ids[d] * EDIM + e];
            }
            v = (cnt > 0) ? (0.5f * w + dsum * inv) : w;
        }
        ushort hu, lu;
        bf16_split(v, hu, lu);
        xr[e] = hu;
        xr[KPAD + e] = hu;
        xr[2 * KPAD + e] = lu;
    }
}

// ---------------------------------------------------------------------------
// Kernel 1b: Wih -> Wcat, row n = [Wh | Wl | Wh]
// ---------------------------------------------------------------------------
__global__ void wcat_kernel(const float* __restrict__ Wih_f,
                            const float* __restrict__ Wih_b,
                            ushort* __restrict__ Wcat) {
    int n = blockIdx.x;
    const float* src = (n < NGATE) ? (Wih_f + (size_t)n * EDIM)
                                   : (Wih_b + (size_t)(n - NGATE) * EDIM);
    ushort* wr = Wcat + (size_t)n * K3;
    for (int e = threadIdx.x; e < KPAD; e += 128) {
        float v = (e < EDIM) ? src[e] : 0.f;
        ushort hu, lu;
        bf16_split(v, hu, lu);
        wr[e] = hu;
        wr[KPAD + e] = lu;
        wr[2 * KPAD + e] = hu;
    }
}

// ---------------------------------------------------------------------------
// Kernel 2: MFMA GEMM (bf16x3), unchanged (verified).
// ---------------------------------------------------------------------------
#define LSTR 40
__global__ __launch_bounds__(256) void gemm_mfma(
        const ushort* __restrict__ Xcat,
        const ushort* __restrict__ Wcat,
        const float* __restrict__ b_f, const float* __restrict__ b_b,
        float* __restrict__ pre) {
    __shared__ ushort Asub[128 * LSTR];
    __shared__ ushort Bsub[128 * LSTR];
    int tid = threadIdx.x;
    int wave = tid >> 6, lane = tid & 63;
    int lid = lane & 15, quad = lane >> 4;
    int m0 = blockIdx.x * 128, n0 = blockIdx.y * 128;
    int wm = (wave >> 1) * 64, wn = (wave & 1) * 64;

    f4v acc[4][4];
#pragma unroll
    for (int i = 0; i < 4; ++i)
#pragma unroll
        for (int j = 0; j < 4; ++j) acc[i][j] = (f4v)0.f;

    float bias[4];
#pragma unroll
    for (int nt = 0; nt < 4; ++nt) {
        int n = n0 + wn + nt * 16 + lid;
        bias[nt] = (n < NGATE) ? b_f[n] : b_b[n - NGATE];
    }

    int c0 = tid, c1 = tid + 256;
    const ushort* aptr0 = Xcat + (size_t)(m0 + (c0 >> 2)) * K3 + (c0 & 3) * 8;
    const ushort* aptr1 = Xcat + (size_t)(m0 + (c1 >> 2)) * K3 + (c1 & 3) * 8;
    const ushort* bptr0 = Wcat + (size_t)(n0 + (c0 >> 2)) * K3 + (c0 & 3) * 8;
    const ushort* bptr1 = Wcat + (size_t)(n0 + (c1 >> 2)) * K3 + (c1 & 3) * 8;
    int la0 = (c0 >> 2) * LSTR + (c0 & 3) * 8;
    int la1 = (c1 >> 2) * LSTR + (c1 & 3) * 8;

    short8 ra0 = *(const short8*)(aptr0);
    short8 ra1 = *(const short8*)(aptr1);
    short8 rb0 = *(const short8*)(bptr0);
    short8 rb1 = *(const short8*)(bptr1);

    for (int k0 = 0; k0 < K3; k0 += 32) {
        __syncthreads();
        *(short8*)&Asub[la0] = ra0;
        *(short8*)&Asub[la1] = ra1;
        *(short8*)&Bsub[la0] = rb0;
        *(short8*)&Bsub[la1] = rb1;
        __syncthreads();
        if (k0 + 32 < K3) {
            ra0 = *(const short8*)(aptr0 + k0 + 32);
            ra1 = *(const short8*)(aptr1 + k0 + 32);
            rb0 = *(const short8*)(bptr0 + k0 + 32);
            rb1 = *(const short8*)(bptr1 + k0 + 32);
        }
        short8 aF[4], bF[4];
#pragma unroll
        for (int mt = 0; mt < 4; ++mt)
            aF[mt] = *(const short8*)&Asub[(wm + mt * 16 + lid) * LSTR + quad * 8];
#pragma unroll
        for (int nt = 0; nt < 4; ++nt)
            bF[nt] = *(const short8*)&Bsub[(wn + nt * 16 + lid) * LSTR + quad * 8];
#pragma unroll
        for (int mt = 0; mt < 4; ++mt)
#pragma unroll
            for (int nt = 0; nt < 4; ++nt)
                acc[mt][nt] = __builtin_amdgcn_mfma_f32_16x16x32_bf16(
                    aF[mt], bF[nt], acc[mt][nt], 0, 0, 0);
    }

#pragma unroll
    for (int mt = 0; mt < 4; ++mt)
#pragma unroll
        for (int nt = 0; nt < 4; ++nt) {
            int n = n0 + wn + nt * 16 + lid;
#pragma unroll
            for (int r = 0; r < 4; ++r) {
                int m = m0 + wm + mt * 16 + quad * 4 + r;
                pre[(size_t)m * NCOLS + n] = acc[mt][nt][r] + bias[nt];
            }
        }
}

// ---------------------------------------------------------------------------
// Kernel 3: LSTM recurrence v8 — v6 structure (256 thr, 4 waves, verified
// 262 us) with instruction-diet on the per-step tail:
//  (a) fused reduce: one asm block of 16 v_add_f32_dpp (ror:4 x8 then
//      ror:8 x8) replaces 48 instrs (mov0+dpp+add per rotate).  s_nop 1
//      guards the VALU->DPP 2-waitstate hazard; intra-block dpp pairs are
//      8 instrs apart (safe).
//  (b) activate-before-broadcast: both of a lane's raw gates are its own
//      type tau, so one uniform formula per lane activates both:
//      e=exp(g*mult), r=rcp(1+e), act=fma(r,sA,sB) with per-lane consts
//      mult{-1,-2}, sA{1,2}, sB{0,-1}  == exact v6 sigm/tanh math.
//      6 trans/step instead of 10.
//  (c) broadcasts of ACTIVATED values via single-instr v_mov_b32_dpp
//      quad_perm (8 instrs, early-clobber outs).
// Layout identical to v6: tau=l&3, ks=(l>>2)&3, hi2=l>>4, hbase=32wv+8hi2;
// lane's gates: (tau, hbase+2ks) [X] and (tau, hbase+2ks+1) [Y];
// lanes tau<2 update hA via X-set, tau>=2 update hA+1 via Y-set.
// ---------------------------------------------------------------------------
__global__ __launch_bounds__(256, 1) void lstm_rec(
        const float* __restrict__ pre,
        const float* __restrict__ Whh_f, const float* __restrict__ Whh_b,
        float* __restrict__ pooled) {
    __shared__ _Float16 h_s[HDIM];
    int t = threadIdx.x;
    int lane = t & 63;
    int wv = t >> 6;
    int tau = lane & 3;
    int ks  = (lane >> 2) & 3;
    int hi2 = lane >> 4;
    int hbase = wv * 32 + hi2 * 8;          // hidx(j) = hbase + j
    int b = blockIdx.x >> 1;
    int dir = blockIdx.x & 1;
    const float* Whh = dir ? Whh_b : Whh_f;

    // f16 weights: w[j][q] = Whh[tau*128 + hbase+j][32ks + 2q, +1]  (128 VGPRs)
    h2 w[8][16];
#pragma unroll
    for (int j = 0; j < 8; ++j) {
        const float* rp = Whh + (size_t)(tau * HDIM + hbase + j) * HDIM + ks * 32;
#pragma unroll
        for (int q = 0; q < 16; ++q) w[j][q] = pk_f16(rp[2 * q], rp[2 * q + 1]);
    }

    float c = 0.f;
    float hmax = -1e30f;
    if (t < 64) ((uint*)h_s)[t] = 0u;       // zero 128 f16

    // owned pre columns: gates (tau, hbase+2ks) and (tau, hbase+2ks+1)
    const float* pX = pre + (size_t)b * S_LEN * NCOLS + dir * NGATE
                    + tau * HDIM + hbase + 2 * ks;
    const float* pY = pX + 1;
    int s = dir ? (S_LEN - 1) : 0;
    int sd = dir ? -1 : 1;
    float pXn1 = pX[(long)s * NCOLS], pYn1 = pY[(long)s * NCOLS];
    float pXn2 = pX[(long)(s + sd) * NCOLS], pYn2 = pY[(long)(s + sd) * NCOLS];

    int hZ = hbase + 2 * ks + (tau >> 1);   // hidx this lane's activation owns
    bool is_g = (tau == 2);
    float mult = is_g ? -2.f : -1.f;        // exp arg scale: sigm e^-g, tanh e^-2g
    float sA   = is_g ?  2.f :  1.f;        // act = fma(rcp, sA, sB)
    float sB   = is_g ? -1.f :  0.f;
    bool oy = (tau & 2) != 0;               // lanes tau>=2 consume the Y-set
    const h2* hp = (const h2*)h_s + ks * 16;

    asm volatile("s_waitcnt lgkmcnt(0)\n\ts_barrier" ::: "memory");

    for (int step = 0; step < S_LEN; ++step) {
        float curX = pXn1, curY = pYn1;
        pXn1 = pXn2; pYn1 = pYn2;
        if (step + 2 < S_LEN) {
            pXn2 = pX[(long)(s + 2 * sd) * NCOLS];
            pYn2 = pY[(long)(s + 2 * sd) * NCOLS];
        }

        // h slice for this lane's k-range: 16 h2 = 64 B = 4 x ds_read_b128
        h2 hh[16];
#pragma unroll
        for (int q = 0; q < 16; ++q) hh[q] = hp[q];

        // 8 partial dots over the owned k-slice (8 independent chains)
        float P[8];
#pragma unroll
        for (int j = 0; j < 8; ++j) {
            float acc = 0.f;
#pragma unroll
            for (int q = 0; q < 16; ++q)
                acc = __builtin_amdgcn_fdot2(w[j][q], hh[q], acc, false);
            P[j] = acc;
        }

        // fused k-combine across the 4 ks lanes: 16 single-instr dpp-adds.
        // ror:8 of row j reads ror:4's result 8 instrs later (hazard-safe);
        // s_nop 1 covers the entry hazard vs the last fdot2 write.
        float R0 = P[0], R1 = P[1], R2 = P[2], R3 = P[3];
        float R4 = P[4], R5 = P[5], R6 = P[6], R7 = P[7];
        asm("s_nop 1\n\t"
            "v_add_f32_dpp %0, %0, %0 row_ror:4 row_mask:0xf bank_mask:0xf\n\t"
            "v_add_f32_dpp %1, %1, %1 row_ror:4 row_mask:0xf bank_mask:0xf\n\t"
            "v_add_f32_dpp %2, %2, %2 row_ror:4 row_mask:0xf bank_mask:0xf\n\t"
            "v_add_f32_dpp %3, %3, %3 row_ror:4 row_mask:0xf bank_mask:0xf\n\t"
            "v_add_f32_dpp %4, %4, %4 row_ror:4 row_mask:0xf bank_mask:0xf\n\t"
            "v_add_f32_dpp %5, %5, %5 row_ror:4 row_mask:0xf bank_mask:0xf\n\t"
            "v_add_f32_dpp %6, %6, %6 row_ror:4 row_mask:0xf bank_mask:0xf\n\t"
            "v_add_f32_dpp %7, %7, %7 row_ror:4 row_mask:0xf bank_mask:0xf\n\t"
            "v_add_f32_dpp %0, %0, %0 row_ror:8 row_mask:0xf bank_mask:0xf\n\t"
            "v_add_f32_dpp %1, %1, %1 row_ror:8 row_mask:0xf bank_mask:0xf\n\t"
            "v_add_f32_dpp %2, %2, %2 row_ror:8 row_mask:0xf bank_mask:0xf\n\t"
            "v_add_f32_dpp %3, %3, %3 row_ror:8 row_mask:0xf bank_mask:0xf\n\t"
            "v_add_f32_dpp %4, %4, %4 row_ror:8 row_mask:0xf bank_mask:0xf\n\t"
            "v_add_f32_dpp %5, %5, %5 row_ror:8 row_mask:0xf bank_mask:0xf\n\t"
            "v_add_f32_dpp %6, %6, %6 row_ror:8 row_mask:0xf bank_mask:0xf\n\t"
            "v_add_f32_dpp %7, %7, %7 row_ror:8 row_mask:0xf bank_mask:0xf"
            : "+v"(R0), "+v"(R1), "+v"(R2), "+v"(R3),
              "+v"(R4), "+v"(R5), "+v"(R6), "+v"(R7));

        // this lane's two owned raw gates (j = 2ks, 2ks+1)
        float X01 = (ks & 1) ? R2 : R0;
        float X23 = (ks & 1) ? R6 : R4;
        float X   = (ks & 2) ? X23 : X01;
        float Y01 = (ks & 1) ? R3 : R1;
        float Y23 = (ks & 1) ? R7 : R5;
        float Y   = (ks & 2) ? Y23 : Y01;
        float gX = X + curX;
        float gY = Y + curY;

        // activate locally (both gates are type tau): exact v6 math.
        float eX = __expf(gX * mult);
        float eY = __expf(gY * mult);
        float rX = __builtin_amdgcn_rcpf(1.f + eX);
        float rY = __builtin_amdgcn_rcpf(1.f + eY);
        float actX = fmaf(rX, sA, sB);
        float actY = fmaf(rY, sA, sB);

        // quad broadcasts of ACTIVATED gates: 8 single-instr mov_dpp.
        float aiX, afX, agX, aoX, aiY, afY, agY, aoY;
        asm("s_nop 1\n\t"
            "v_mov_b32_dpp %0, %8 quad_perm:[0,0,0,0] row_mask:0xf bank_mask:0xf\n\t"
            "v_mov_b32_dpp %4, %9 quad_perm:[0,0,0,0] row_mask:0xf bank_mask:0xf\n\t"
            "v_mov_b32_dpp %1, %8 quad_perm:[1,1,1,1] row_mask:0xf bank_mask:0xf\n\t"
            "v_mov_b32_dpp %5, %9 quad_perm:[1,1,1,1] row_mask:0xf bank_mask:0xf\n\t"
            "v_mov_b32_dpp %2, %8 quad_perm:[2,2,2,2] row_mask:0xf bank_mask:0xf\n\t"
            "v_mov_b32_dpp %6, %9 quad_perm:[2,2,2,2] row_mask:0xf bank_mask:0xf\n\t"
            "v_mov_b32_dpp %3, %8 quad_perm:[3,3,3,3] row_mask:0xf bank_mask:0xf\n\t"
            "v_mov_b32_dpp %7, %9 quad_perm:[3,3,3,3] row_mask:0xf bank_mask:0xf"
            : "=&v"(aiX), "=&v"(afX), "=&v"(agX), "=&v"(aoX),
              "=&v"(aiY), "=&v"(afY), "=&v"(agY), "=&v"(aoY)
            : "v"(actX), "v"(actY));

        // lanes tau<2 consume X-set (hidx hA), tau>=2 the Y-set (hA+1)
        float ai = oy ? aiY : aiX;
        float af = oy ? afY : afX;
        float ag = oy ? agY : agX;
        float ao = oy ? aoY : aoX;

        c = fmaf(af, c, ai * ag);
        float ec = __expf(-2.f * c);
        float rc = __builtin_amdgcn_rcpf(1.f + ec);
        float h  = ao * fmaf(rc, 2.f, -1.f);   // ao * tanh(c)
        hmax = fmaxf(hmax, h);

        if ((tau & 1) == 0) h_s[hZ] = (_Float16)h;   // tau 0 & 2 write
        asm volatile("s_waitcnt lgkmcnt(0)\n\ts_barrier" ::: "memory");
        s += sd;
    }

    if ((tau & 1) == 0) pooled[b * 256 + dir * HDIM + hZ] = hmax;
}

// ---------------------------------------------------------------------------
// Kernel 4: classifier (unchanged)
// ---------------------------------------------------------------------------
__global__ void cls_kernel(const float* __restrict__ pooled,
                           const float* __restrict__ W_cls,
                           const float* __restrict__ b_cls,
                           float* __restrict__ out) {
    int i = threadIdx.x;
    if (i < BATCH * 5) {
        int b = i / 5, l = i % 5;
        float acc = b_cls[l];
        const float* p = pooled + b * 256;
        const float* w = W_cls + l * 256;
#pragma unroll 8
        for (int j = 0; j < 256; ++j) acc = fmaf(p[j], w[j], acc);
        out[i] = acc;
    }
}

// ---------------------------------------------------------------------------
extern "C" void kernel_launch(void* const* d_in, const int* in_sizes, int n_in,
                              void* d_out, int out_size, void* d_ws, size_t ws_size,
                              hipStream_t stream) {
    const int*   word_ids   = (const int*)d_in[0];
    const int*   deps_ids   = (const int*)d_in[1];
    const float* word_table = (const float*)d_in[2];
    const float* dep_table  = (const float*)d_in[3];
    const float* Wih_f      = (const float*)d_in[4];
    const float* Whh_f      = (const float*)d_in[5];
    const float* b_f        = (const float*)d_in[6];
    const float* Wih_b      = (const float*)d_in[7];
    const float* Whh_b      = (const float*)d_in[8];
    const float* b_b        = (const float*)d_in[9];
    const float* W_cls      = (const float*)d_in[10];
    const float* b_cls      = (const float*)d_in[11];
    float* out = (float*)d_out;

    float*  pre    = (float*)d_ws;
    float*  pooled = pre + (size_t)BATCH * S_LEN * NCOLS;
    ushort* Xcat   = (ushort*)(pooled + BATCH * 256);
    ushort* Wcat   = Xcat + (size_t)BATCH * S_LEN * K3;

    embed_xcat<<<BATCH * S_LEN, 128, 0, stream>>>(word_ids, deps_ids,
                                                  word_table, dep_table, Xcat);
    wcat_kernel<<<NCOLS, 128, 0, stream>>>(Wih_f, Wih_b, Wcat);
    gemm_mfma<<<dim3(128, 8), 256, 0, stream>>>(Xcat, Wcat, b_f, b_b, pre);
    lstm_rec<<<64, 256, 0, stream>>>(pre, Whh_f, Whh_b, pooled);
    cls_kernel<<<1, 192, 0, stream>>>(pooled, W_cls, b_cls, out);
}